// Round 4
// baseline (124.977 us; speedup 1.0000x reference)
//
#include <hip/hip_runtime.h>
#include <stdint.h>

// 7x7 conv, stride 1, pad 3, on 64 x 512 x 512 fp32 (single channel).
// out[n,y,x] = sum_{ky,kx} x[n, y+ky-3, x+kx-3] * w[ky,kx]
//
// R11: 2-phase software pipeline (T3 minimum recipe) over 4 y-stacked tiles.
//   - R10 analysis: per-pipe floors VALU ~10.5us, LDS ~5us, HBM ~19us, but
//     measured ~35us at VALUBusy 37% / HBM 35% -> NO pipe saturated. The
//     serial stage -> barrier(vmcnt0) -> compute chain per block is the
//     bottleneck (latency-bound), not pipe width.
//   - Each block now owns 4 vertically-adjacent TH=16 tiles with a
//     double-buffered LDS: stage(t+1) issues BEFORE compute(t), so HBM
//     latency hides under ~2.5k cycles of FMA; one barrier per tile.
//   - Buffer rotation safety: the single barrier per iter (a) drains the
//     global_load_lds prefetch for tile t+1, and (b) fences all reads of
//     buf[cur] (compute(t) is pre-barrier) before iter t+1 stages into it.
//   - Stage/compute/store bodies byte-identical to passing R10 (full-exec
//     global_load_lds, laundered b64 reads, same FMA order -> same numerics).
//   - LDS 2 x 23,232 B = 46,464 B -> 3 blocks/CU resident; grid 1024 blocks.

#define IMG_W 512
#define IMG_H 512
#define NIMG  64
#define TW    256            // output tile width per block
#define TH    16             // output tile height per tile
#define TILES_Y 4            // y-stacked tiles per block (pipelined)
#define HALO  3
#define LDS_W 264            // floats per row: tile col c <-> global x = bx-4+c
#define LDS_H (TH + 2*HALO)  // 22 rows
#define TILE_F (LDS_H * LDS_W)

// async 16B global -> LDS (dest must be uniform base + lane*16, FULL exec)
__device__ __forceinline__ void gload_lds16(const float* src, float* dst_lds)
{
    __builtin_amdgcn_global_load_lds(
        (__attribute__((address_space(1))) void*)(uintptr_t)src,
        (__attribute__((address_space(3))) void*)(uintptr_t)dst_lds,
        16, 0, 0);
}

// Stage one 22-row tile into `buf`. Interior rows: full-exec global_load_lds
// per row (gy guard is wave-uniform); edges: guarded VGPR path from tid<44.
__device__ __forceinline__ void stage_tile(float* buf, const float* __restrict__ img,
                                           int bx, int by, int wave, int lane, int tid)
{
    for (int r = wave; r < LDS_H; r += 4) {
        const int gy = by - HALO + r;
        float* dst = &buf[r * LDS_W + 4 + 4 * lane];
        if ((unsigned)gy < IMG_H) {
            gload_lds16(&img[(size_t)gy * IMG_W + bx + 4 * lane], dst);
        } else {
            *(float4*)dst = make_float4(0.f, 0.f, 0.f, 0.f);  // contiguous write
        }
    }
    if (tid < 2 * LDS_H) {
        const int r    = tid >> 1;
        const int side = tid & 1;
        const int cb   = side ? (LDS_W - 4) : 0;
        const int gx   = side ? (bx + 256) : (bx - 4);
        const int gy   = by - HALO + r;
        float4 v = make_float4(0.f, 0.f, 0.f, 0.f);
        if (((unsigned)gy < IMG_H) && ((unsigned)gx < IMG_W))
            v = *(const float4*)&img[(size_t)gy * IMG_W + gx];
        *(float4*)&buf[r * LDS_W + cb] = v;
    }
}

__global__ __launch_bounds__(256, 3) void conv7x7_kernel(
    const float* __restrict__ x,
    const float* __restrict__ wgt,
    float* __restrict__ out)
{
    __shared__ float tile[2 * TILE_F];   // 46,464 B, double-buffered

    const int tid  = threadIdx.x;
    const int wave = tid >> 6;
    const int lane = tid & 63;
    const int bx   = blockIdx.x * TW;
    const int by0  = blockIdx.y * (TH * TILES_Y);
    const int n    = blockIdx.z;

    const float* img = x + (size_t)n * (IMG_W * IMG_H);
    float* o = out + (size_t)n * (IMG_W * IMG_H);

    // ---- weights: wave-uniform -> SGPRs (s_loads overlap staging) ----
    float w[49];
    #pragma unroll
    for (int i = 0; i < 49; ++i) w[i] = wgt[i];

    const int lx = lane * 4;        // output x within tile
    const int rbase = wave * 4;

    // Laundered 8-byte deltas: opaque to the vectorizer -> loads stay as
    // individual ds_read_b64 (the conflict-free width), not re-merged b128.
    int d[6];
    #pragma unroll
    for (int t = 0; t < 6; ++t) {
        d[t] = t * 8;
        asm volatile("" : "+v"(d[t]));
    }

    // ---- prologue: stage tile 0 ----
    stage_tile(&tile[0], img, bx, by0, wave, lane, tid);
    __syncthreads();   // drains vmcnt (global_load_lds) + lgkmcnt

    int cur = 0;
    #pragma unroll
    for (int t = 0; t < TILES_Y; ++t) {
        // ---- prefetch next tile into the other buffer ----
        if (t < TILES_Y - 1)
            stage_tile(&tile[(cur ^ 1) * TILE_F], img, bx, by0 + (t + 1) * TH,
                       wave, lane, tid);

        // ---- compute current tile: 4x x 4y per thread, 6 b64 per row ----
        const int by = by0 + t * TH;
        const char* tb = (const char*)&tile[cur * TILE_F]
                       + (size_t)(rbase * LDS_W + lx) * 4;

        float acc[4][4] = {};

        #pragma unroll
        for (int r = 0; r < 10; ++r) {
            const char* rowb = tb + (size_t)r * (LDS_W * 4);
            float2 q[6];
            #pragma unroll
            for (int u = 0; u < 6; ++u)
                q[u] = *(const float2*)(rowb + d[u]);
            const float row[12] = {q[0].x, q[0].y, q[1].x, q[1].y,
                                   q[2].x, q[2].y, q[3].x, q[3].y,
                                   q[4].x, q[4].y, q[5].x, q[5].y};
            #pragma unroll
            for (int j = 0; j < 4; ++j) {
                const int ky = r - j;
                if (ky >= 0 && ky < 7) {
                    #pragma unroll
                    for (int kx = 0; kx < 7; ++kx) {
                        const float wv = w[ky * 7 + kx];
                        #pragma unroll
                        for (int cc = 0; cc < 4; ++cc)
                            acc[j][cc] = fmaf(row[1 + kx + cc], wv, acc[j][cc]);
                    }
                }
            }
        }

        // ---- store: 4 rows of float4 per thread (contiguous per wave) ----
        #pragma unroll
        for (int j = 0; j < 4; ++j) {
            float4 v = make_float4(acc[j][0], acc[j][1], acc[j][2], acc[j][3]);
            *(float4*)&o[(size_t)(by + rbase + j) * IMG_W + bx + lx] = v;
        }

        // One barrier per tile: (a) waits prefetch of t+1 (vmcnt drain),
        // (b) fences reads of buf[cur] before t+2 overwrites it.
        __syncthreads();
        cur ^= 1;
    }
}

extern "C" void kernel_launch(void* const* d_in, const int* in_sizes, int n_in,
                              void* d_out, int out_size, void* d_ws, size_t ws_size,
                              hipStream_t stream)
{
    const float* x   = (const float*)d_in[0];
    const float* wgt = (const float*)d_in[1];
    float* out       = (float*)d_out;

    // x: 512/256 = 2, y: 512/(16*4) = 8, z: 64  -> 1024 blocks
    dim3 grid(IMG_W / TW, IMG_H / (TH * TILES_Y), NIMG);
    conv7x7_kernel<<<grid, 256, 0, stream>>>(x, wgt, out);
}

// Round 5
// 119.312 us; speedup vs baseline: 1.0475x; 1.0475x over previous
//
#include <hip/hip_runtime.h>
#include <stdint.h>

// 7x7 conv, stride 1, pad 3, on 64 x 512 x 512 fp32 (single channel).
// out[n,y,x] = sum_{ky,kx} x[n, y+ky-3, x+kx-3] * w[ky,kx]
//
// R12: full-width blocks (TW=512) -> no inter-block x-halo -> no divergent
// edge-staging path; all staging is full-exec global_load_lds.
//   - R11 post-mortem: in-block pipelining cut the grid to 1024 blocks and
//     occupancy collapsed to 20% (1.6 blocks/CU) -> stalls LESS hidden.
//     Cross-block TLP, not in-block ILP, is what hides latency here.
//   - R9/R10 critical-path culprit: the tid<44 edge path (global->VGPR->
//     ds_write) put an HBM round-trip on wave 0 before every barrier.
//     TW=512 makes the x-halo the IMAGE border = constant zeros, written
//     once as 44 zero-float4 ds_writes (no loads, no vmcnt dependency).
//   - 512 threads (8 waves: wx = wave&1 covers x halves, wy = wave>>1),
//     4x4 outputs/thread, laundered ds_read_b64 compute (R10), same FMA
//     order -> identical numerics.
//   - LDS 22 x 520 x 4 = 45,760 B -> 3 blocks/CU = 24 waves/CU resident
//     (was ~14.7). Single-shot stage -> barrier -> compute; grid 2048.

#define IMG_W 512
#define IMG_H 512
#define NIMG  64
#define TW    512            // full image width per block
#define TH    16             // output tile height per block
#define HALO  3
#define LDS_W 520            // tile col c <-> global x = c - 4 (4 pad each side)
#define LDS_H (TH + 2*HALO)  // 22 rows

// async 16B global -> LDS (dest must be uniform base + lane*16, FULL exec)
__device__ __forceinline__ void gload_lds16(const float* src, float* dst_lds)
{
    __builtin_amdgcn_global_load_lds(
        (__attribute__((address_space(1))) void*)(uintptr_t)src,
        (__attribute__((address_space(3))) void*)(uintptr_t)dst_lds,
        16, 0, 0);
}

__global__ __launch_bounds__(512, 6) void conv7x7_kernel(
    const float* __restrict__ x,
    const float* __restrict__ wgt,
    float* __restrict__ out)
{
    __shared__ float tile[LDS_H * LDS_W];   // 45,760 B, linear

    const int tid  = threadIdx.x;
    const int wave = tid >> 6;
    const int lane = tid & 63;
    const int by   = blockIdx.x * TH;
    const int n    = blockIdx.y;

    const float* img = x + (size_t)n * (IMG_W * IMG_H);
    float* o = out + (size_t)n * (IMG_W * IMG_H);

    // ---- weights: wave-uniform -> SGPRs (s_loads overlap staging) ----
    float w[49];
    #pragma unroll
    for (int i = 0; i < 49; ++i) w[i] = wgt[i];

    // ---- constant zero x-pads: cols 0..3 and 516..519 of each row ----
    // (gx = -4..-1 and 512..515: always outside the image -> always zero)
    if (tid < 2 * LDS_H) {
        const int r    = tid >> 1;
        const int side = tid & 1;
        *(float4*)&tile[r * LDS_W + side * (LDS_W - 4)] =
            make_float4(0.f, 0.f, 0.f, 0.f);
    }

    // ---- stage 22 rows x 2 half-rows, all full-exec global_load_lds ----
    // i = wave + 8k -> r = i>>1 and half = i&1 are wave-uniform.
    for (int i = wave; i < 2 * LDS_H; i += 8) {
        const int r    = i >> 1;
        const int half = i & 1;
        const int gy   = by - HALO + r;
        float* dst = &tile[r * LDS_W + 4 + half * 256 + 4 * lane];
        if ((unsigned)gy < IMG_H) {
            gload_lds16(&img[(size_t)gy * IMG_W + half * 256 + 4 * lane], dst);
        } else {
            *(float4*)dst = make_float4(0.f, 0.f, 0.f, 0.f);  // zero pad row
        }
    }

    __syncthreads();   // drains vmcnt (global_load_lds) + lgkmcnt

    // ---- compute: 4x x 4y outputs per thread, 6 ds_read_b64 per row ----
    const int wx = wave & 1;
    const int wy = wave >> 1;
    const int lx = wx * 256 + lane * 4;   // output x (== tile col of output)
    const int rbase = wy * 4;

    // Laundered 8-byte deltas: opaque to the vectorizer -> loads stay as
    // individual ds_read_b64 (2 dwords/lane = the conflict-free width).
    int d[6];
    #pragma unroll
    for (int t = 0; t < 6; ++t) {
        d[t] = t * 8;
        asm volatile("" : "+v"(d[t]));
    }

    // need tile cols lx+1 .. lx+10 (input gx = ox-3..ox+3 union, c = gx+4);
    // read cols lx .. lx+11 as 6 overlapping-free b64.
    const char* tb = (const char*)tile + (size_t)(rbase * LDS_W + lx) * 4;

    float acc[4][4] = {};

    #pragma unroll
    for (int r = 0; r < 10; ++r) {
        const char* rowb = tb + (size_t)r * (LDS_W * 4);
        float2 q[6];
        #pragma unroll
        for (int u = 0; u < 6; ++u)
            q[u] = *(const float2*)(rowb + d[u]);
        const float row[12] = {q[0].x, q[0].y, q[1].x, q[1].y,
                               q[2].x, q[2].y, q[3].x, q[3].y,
                               q[4].x, q[4].y, q[5].x, q[5].y};
        #pragma unroll
        for (int j = 0; j < 4; ++j) {
            const int ky = r - j;
            if (ky >= 0 && ky < 7) {
                #pragma unroll
                for (int kx = 0; kx < 7; ++kx) {
                    const float wv = w[ky * 7 + kx];
                    #pragma unroll
                    for (int cc = 0; cc < 4; ++cc)
                        acc[j][cc] = fmaf(row[1 + kx + cc], wv, acc[j][cc]);
                }
            }
        }
    }

    // ---- store: 4 rows of float4 per thread (contiguous per wave) ----
    #pragma unroll
    for (int j = 0; j < 4; ++j) {
        float4 v = make_float4(acc[j][0], acc[j][1], acc[j][2], acc[j][3]);
        *(float4*)&o[(size_t)(by + rbase + j) * IMG_W + lx] = v;
    }
}

extern "C" void kernel_launch(void* const* d_in, const int* in_sizes, int n_in,
                              void* d_out, int out_size, void* d_ws, size_t ws_size,
                              hipStream_t stream)
{
    const float* x   = (const float*)d_in[0];
    const float* wgt = (const float*)d_in[1];
    float* out       = (float*)d_out;

    // y-tiles: 512/16 = 32, images: 64 -> 2048 blocks of 512 threads
    dim3 grid(IMG_H / TH, NIMG, 1);
    conv7x7_kernel<<<grid, 512, 0, stream>>>(x, wgt, out);
}